// Round 1
// baseline (314.264 us; speedup 1.0000x reference)
//
#include <hip/hip_runtime.h>

// Sparse COO (32x64, nnz=3) @ dense x (64, N) -> out (32, N), fp32.
// Memory-bound: must write all 128 MB of out (harness poisons it), read ~12 MB of x.
// One thread per (row, 4-col chunk). blockIdx.y = row => rows[k]==r is wave-uniform.

__global__ __launch_bounds__(256) void spmm_coo_vec4(
    const float4* __restrict__ x4,      // (64, ncols4) as float4
    const float* __restrict__ values,   // (nnz,)
    const int* __restrict__ rows,       // (nnz,)
    const int* __restrict__ cols,       // (nnz,)
    float4* __restrict__ out4,          // (32, ncols4) as float4
    int ncols4, int nnz)
{
    int c4 = blockIdx.x * blockDim.x + threadIdx.x;
    if (c4 >= ncols4) return;
    int r = blockIdx.y;

    float4 acc = make_float4(0.f, 0.f, 0.f, 0.f);
    for (int k = 0; k < nnz; ++k) {
        // rows[k], cols[k], values[k] are uniform loads (L2-cached, broadcast).
        if (rows[k] == r) {   // wave-uniform branch: r is uniform per block
            float v = values[k];
            float4 xv = x4[(long long)cols[k] * ncols4 + c4];
            acc.x += v * xv.x;
            acc.y += v * xv.y;
            acc.z += v * xv.z;
            acc.w += v * xv.w;
        }
    }
    out4[(long long)r * ncols4 + c4] = acc;
}

// Scalar fallback in case N is not divisible by 4 (not the case here, but safe).
__global__ __launch_bounds__(256) void spmm_coo_scalar(
    const float* __restrict__ x,
    const float* __restrict__ values,
    const int* __restrict__ rows,
    const int* __restrict__ cols,
    float* __restrict__ out,
    int ncols, int nnz)
{
    int c = blockIdx.x * blockDim.x + threadIdx.x;
    if (c >= ncols) return;
    int r = blockIdx.y;

    float acc = 0.f;
    for (int k = 0; k < nnz; ++k) {
        if (rows[k] == r) {
            acc += values[k] * x[(long long)cols[k] * ncols + c];
        }
    }
    out[(long long)r * ncols + c] = acc;
}

extern "C" void kernel_launch(void* const* d_in, const int* in_sizes, int n_in,
                              void* d_out, int out_size, void* d_ws, size_t ws_size,
                              hipStream_t stream) {
    const float* x      = (const float*)d_in[0];
    const float* values = (const float*)d_in[1];
    const int*   rows   = (const int*)d_in[2];
    const int*   cols   = (const int*)d_in[3];
    float* out = (float*)d_out;

    const int OUT_FEATURES = 32;
    const int nnz = in_sizes[1];
    const int ncols = out_size / OUT_FEATURES;   // 1,000,000

    if ((ncols & 3) == 0) {
        int ncols4 = ncols >> 2;                 // 250,000 float4 per row
        dim3 block(256);
        dim3 grid((ncols4 + 255) / 256, OUT_FEATURES);
        spmm_coo_vec4<<<grid, block, 0, stream>>>(
            (const float4*)x, values, rows, cols, (float4*)out, ncols4, nnz);
    } else {
        dim3 block(256);
        dim3 grid((ncols + 255) / 256, OUT_FEATURES);
        spmm_coo_scalar<<<grid, block, 0, stream>>>(
            x, values, rows, cols, out, ncols, nnz);
    }
}